// Round 1
// baseline (2417.296 us; speedup 1.0000x reference)
//
#include <hip/hip_runtime.h>

#define D 64
constexpr int U_ = 50000, B_ = 20000, I_ = 40000;

// Copy concat([A;B]) into f, and initialize acc (layer-0 raw features) split
// across accA (rows < nA) / accB (rows >= nA). float4-vectorized.
__global__ void k_init(const float* __restrict__ A, const float* __restrict__ Bf,
                       int nA, int n, float* __restrict__ f,
                       float* __restrict__ accA, float* __restrict__ accB) {
    int t = blockIdx.x * blockDim.x + threadIdx.x;   // over n * (D/4)
    if (t >= n * (D / 4)) return;
    int row = t >> 4;        // D/4 = 16 float4 per row
    int c4  = t & 15;
    float4 v;
    if (row < nA) v = ((const float4*)A)[(size_t)row * 16 + c4];
    else          v = ((const float4*)Bf)[(size_t)(row - nA) * 16 + c4];
    ((float4*)f)[t] = v;
    if (row < nA) ((float4*)accA)[(size_t)row * 16 + c4] = v;
    else          ((float4*)accB)[(size_t)(row - nA) * 16 + c4] = v;
}

// COO SpMM: one 64-lane wave per edge. y[r,:] += val * x[c,:]
// Edge metadata loads are wave-uniform (broadcast); row accesses coalesced.
__global__ void k_spmm(const int* __restrict__ rows, const int* __restrict__ cols,
                       const float* __restrict__ val, int nnz,
                       const float* __restrict__ x, float* __restrict__ y) {
    int e = (blockIdx.x << 2) + (threadIdx.x >> 6);   // 4 edges / 256-thr block
    if (e >= nnz) return;
    int lane = threadIdx.x & 63;
    int r = rows[e];
    int c = cols[e];
    float v = val[e];
    unsafeAtomicAdd(&y[(size_t)r * D + lane], v * x[(size_t)c * D + lane]);
}

// f *= inv (the /(i+2)); acc += f / max(||f||_2, 1e-12). One wave per row.
__global__ void k_norm_acc(float* __restrict__ f, int nA, int n, float inv,
                           float* __restrict__ accA, float* __restrict__ accB) {
    int row = (blockIdx.x << 2) + (threadIdx.x >> 6);
    if (row >= n) return;
    int lane = threadIdx.x & 63;
    float v = f[(size_t)row * D + lane] * inv;
    f[(size_t)row * D + lane] = v;       // carried into next layer's SpMM
    float s = v * v;
    #pragma unroll
    for (int off = 32; off; off >>= 1) s += __shfl_xor(s, off, 64);
    float r = v / fmaxf(sqrtf(s), 1e-12f);
    if (row < nA) accA[(size_t)row * D + lane] += r;
    else          accB[(size_t)(row - nA) * D + lane] += r;
}

extern "C" void kernel_launch(void* const* d_in, const int* in_sizes, int n_in,
                              void* d_out, int out_size, void* d_ws, size_t ws_size,
                              hipStream_t stream) {
    const float* users   = (const float*)d_in[0];
    const float* bundles = (const float*)d_in[1];
    const float* items   = (const float*)d_in[2];
    const int*   ui_idx  = (const int*)d_in[3];
    const float* ui_val  = (const float*)d_in[4];
    const int*   ub_idx  = (const int*)d_in[5];
    const float* ub_val  = (const float*)d_in[6];
    const int*   ubx_idx = (const int*)d_in[7];
    const float* ubx_val = (const float*)d_in[8];
    const int*   agg_idx = (const int*)d_in[9];
    const float* agg_val = (const float*)d_in[10];
    const int ui_nnz  = in_sizes[4];   // 2*E_UI  (symmetrized)
    const int ub_nnz  = in_sizes[6];
    const int ubx_nnz = in_sizes[8];
    const int agg_nnz = in_sizes[10];

    float* out = (float*)d_out;

    // workspace: f/g ping-pong (90000*64 each) + items accumulator (40000*64)
    const size_t NMAX = (size_t)(U_ + I_) * D;       // 5,760,000 floats
    float* fbuf    = (float*)d_ws;
    float* gbuf    = fbuf + NMAX;
    float* acc_itm = gbuf + NMAX;                    // I_*D floats

    // out layout (float offsets)
    float* out_IL_u = out;
    float* out_BL_u = out + (size_t)U_ * D;
    float* out_XL_u = out + (size_t)2 * U_ * D;
    float* out_IL_b = out + (size_t)3 * U_ * D;
    float* out_BL_b = out + (size_t)3 * U_ * D + (size_t)B_ * D;
    float* out_XL_b = out + (size_t)3 * U_ * D + (size_t)2 * B_ * D;

    auto propagate = [&](const int* idxp, const float* valp, int nnz,
                         const float* Bfeat, int nB, float* accA, float* accB) {
        const int n = U_ + nB;
        const size_t bytes = (size_t)n * D * sizeof(float);
        const int* rows = idxp;
        const int* cols = idxp + nnz;

        hipLaunchKernelGGL(k_init, dim3((n * 16 + 255) / 256), dim3(256), 0, stream,
                           users, Bfeat, U_, n, fbuf, accA, accB);
        // layer 0: g = spmm(f)/2 ; acc += l2norm(g)
        hipMemsetAsync(gbuf, 0, bytes, stream);
        hipLaunchKernelGGL(k_spmm, dim3((nnz + 3) / 4), dim3(256), 0, stream,
                           rows, cols, valp, nnz, fbuf, gbuf);
        hipLaunchKernelGGL(k_norm_acc, dim3((n + 3) / 4), dim3(256), 0, stream,
                           gbuf, U_, n, 0.5f, accA, accB);
        // layer 1: f = spmm(g)/3 ; acc += l2norm(f)
        hipMemsetAsync(fbuf, 0, bytes, stream);
        hipLaunchKernelGGL(k_spmm, dim3((nnz + 3) / 4), dim3(256), 0, stream,
                           rows, cols, valp, nnz, gbuf, fbuf);
        hipLaunchKernelGGL(k_norm_acc, dim3((n + 3) / 4), dim3(256), 0, stream,
                           fbuf, U_, n, 1.0f / 3.0f, accA, accB);
    };

    // item-level propagation over user-item graph (acc users -> out, items -> ws)
    propagate(ui_idx, ui_val, ui_nnz, items, I_, out_IL_u, acc_itm);

    // bundle aggregation: IL_b = spmm(agg, IL_i)  (single-direction edges)
    hipMemsetAsync(out_IL_b, 0, (size_t)B_ * D * sizeof(float), stream);
    hipLaunchKernelGGL(k_spmm, dim3((agg_nnz + 3) / 4), dim3(256), 0, stream,
                       agg_idx, agg_idx + agg_nnz, agg_val, agg_nnz,
                       acc_itm, out_IL_b);

    // bundle-level propagation over user-bundle graph
    propagate(ub_idx, ub_val, ub_nnz, bundles, B_, out_BL_u, out_BL_b);

    // ingredient-augmented user-bundle propagation
    propagate(ubx_idx, ubx_val, ubx_nnz, bundles, B_, out_XL_u, out_XL_b);
}

// Round 2
// 1893.736 us; speedup vs baseline: 1.2765x; 1.2765x over previous
//
#include <hip/hip_runtime.h>

#define D 64
constexpr int U_ = 50000, B_ = 20000, I_ = 40000;

// ---------------- CSR build (per call, per graph) ----------------

__global__ void k_hist(const int* __restrict__ rows, int nnz, int* __restrict__ cnt) {
    int e = blockIdx.x * blockDim.x + threadIdx.x;
    if (e < nnz) atomicAdd(&cnt[rows[e]], 1);
}

// Single-block exclusive scan over n counts (n <= ~90000).
// In: cnt_cursor = per-row counts. Out: rowstart[0..n] = offsets,
// cnt_cursor rewritten to start offsets (scatter cursors).
__global__ void k_scan(int* __restrict__ cnt_cursor, int n, int* __restrict__ rowstart) {
    __shared__ int part[1024];
    int t = threadIdx.x;
    int chunk = (n + 1023) / 1024;
    int s0 = min(t * chunk, n), s1 = min(s0 + chunk, n);
    int sum = 0;
    for (int i = s0; i < s1; i++) sum += cnt_cursor[i];
    part[t] = sum;
    __syncthreads();
    for (int off = 1; off < 1024; off <<= 1) {   // Hillis-Steele inclusive
        int v = (t >= off) ? part[t - off] : 0;
        __syncthreads();
        part[t] += v;
        __syncthreads();
    }
    int run = (t == 0) ? 0 : part[t - 1];
    for (int i = s0; i < s1; i++) {
        int c = cnt_cursor[i];
        rowstart[i] = run;
        cnt_cursor[i] = run;
        run += c;
    }
    if (t == 0) rowstart[n] = part[1023];
}

__global__ void k_scatter(const int* __restrict__ rows, const int* __restrict__ cols,
                          const float* __restrict__ val, int nnz,
                          int* __restrict__ cursor, int* __restrict__ ecol,
                          float* __restrict__ eval) {
    int e = blockIdx.x * blockDim.x + threadIdx.x;
    if (e >= nnz) return;
    int pos = atomicAdd(&cursor[rows[e]], 1);
    ecol[pos] = cols[e];
    eval[pos] = val[e];
}

// ---------------- fused CSR-SpMM + scale + l2norm + acc ----------------
// One 64-lane wave per destination row. Gather x rows (wave-uniform col ->
// coalesced 256B read), accumulate in registers, then scale by inv, write
// f-out, shfl-reduce the L2 norm, and accumulate the normalized row into
// accA/accB. No atomics anywhere.
__global__ void k_layer(const int* __restrict__ rowstart, const int* __restrict__ ecol,
                        const float* __restrict__ eval, int n, int nsplit,
                        const float* __restrict__ xA, const float* __restrict__ xB_adj,
                        float inv, float* __restrict__ fout,
                        float* __restrict__ accA, float* __restrict__ accB) {
    int row = (blockIdx.x << 2) + (threadIdx.x >> 6);
    if (row >= n) return;
    int lane = threadIdx.x & 63;
    int s = rowstart[row], e = rowstart[row + 1];
    float acc = 0.f;
    for (int base = s; base < e; base += 64) {
        int jn = e - base; if (jn > 64) jn = 64;
        int li = base + (lane < jn ? lane : jn - 1);   // clamped vector load
        int   cj = ecol[li];
        float vj = eval[li];
        for (int j = 0; j < jn; j++) {
            int   c = __shfl(cj, j, 64);
            float v = __shfl(vj, j, 64);
            const float* xp = (c < nsplit) ? xA : xB_adj;   // wave-uniform select
            acc += v * xp[(size_t)c * D + lane];
        }
    }
    float v = acc * inv;
    fout[(size_t)row * D + lane] = v;
    float sq = v * v;
    #pragma unroll
    for (int off = 32; off; off >>= 1) sq += __shfl_xor(sq, off, 64);
    float r = v / fmaxf(sqrtf(sq), 1e-12f);
    if (row < U_) accA[(size_t)row * D + lane] += r;
    else          accB[(size_t)(row - U_) * D + lane] += r;
}

// Plain CSR-SpMM (bundle aggregation): y[row] = sum val * x[col]
__global__ void k_spmm_csr(const int* __restrict__ rowstart, const int* __restrict__ ecol,
                           const float* __restrict__ eval, int n,
                           const float* __restrict__ x, float* __restrict__ y) {
    int row = (blockIdx.x << 2) + (threadIdx.x >> 6);
    if (row >= n) return;
    int lane = threadIdx.x & 63;
    int s = rowstart[row], e = rowstart[row + 1];
    float acc = 0.f;
    for (int base = s; base < e; base += 64) {
        int jn = e - base; if (jn > 64) jn = 64;
        int li = base + (lane < jn ? lane : jn - 1);
        int   cj = ecol[li];
        float vj = eval[li];
        for (int j = 0; j < jn; j++) {
            int   c = __shfl(cj, j, 64);
            float v = __shfl(vj, j, 64);
            acc += v * x[(size_t)c * D + lane];
        }
    }
    y[(size_t)row * D + lane] = acc;
}

extern "C" void kernel_launch(void* const* d_in, const int* in_sizes, int n_in,
                              void* d_out, int out_size, void* d_ws, size_t ws_size,
                              hipStream_t stream) {
    const float* users   = (const float*)d_in[0];
    const float* bundles = (const float*)d_in[1];
    const float* items   = (const float*)d_in[2];
    const int*   ui_idx  = (const int*)d_in[3];
    const float* ui_val  = (const float*)d_in[4];
    const int*   ub_idx  = (const int*)d_in[5];
    const float* ub_val  = (const float*)d_in[6];
    const int*   ubx_idx = (const int*)d_in[7];
    const float* ubx_val = (const float*)d_in[8];
    const int*   agg_idx = (const int*)d_in[9];
    const float* agg_val = (const float*)d_in[10];
    const int ui_nnz  = in_sizes[4];
    const int ub_nnz  = in_sizes[6];
    const int ubx_nnz = in_sizes[8];
    const int agg_nnz = in_sizes[10];

    float* out = (float*)d_out;
    const size_t rowf = (size_t)D;

    // ---- workspace carve-up (floats/ints) ----
    const size_t NMAX   = (size_t)(U_ + I_) * D;      // 5.76M floats
    const int    NNZMAX = 2000000;                    // ui graph (largest)
    float* fbuf    = (float*)d_ws;                    // 23.04 MB
    float* gbuf    = fbuf + NMAX;                     // 23.04 MB
    float* acc_itm = gbuf + NMAX;                     // 10.24 MB
    float* eval    = acc_itm + (size_t)I_ * D;        //  8.0 MB
    int*   ecol    = (int*)(eval + NNZMAX);           //  8.0 MB
    int*   rowstart= ecol + NNZMAX;                   //  ~0.36 MB
    int*   cursor  = rowstart + (U_ + I_ + 1);        //  ~0.36 MB

    // ---- output layout ----
    float* out_IL_u = out;
    float* out_BL_u = out + (size_t)U_ * rowf;
    float* out_XL_u = out + (size_t)2 * U_ * rowf;
    float* out_IL_b = out + (size_t)3 * U_ * rowf;
    float* out_BL_b = out + (size_t)3 * U_ * rowf + (size_t)B_ * rowf;
    float* out_XL_b = out + (size_t)3 * U_ * rowf + (size_t)2 * B_ * rowf;

    auto build_csr = [&](const int* idxp, const float* valp, int nnz, int n) {
        hipMemsetAsync(cursor, 0, (size_t)n * sizeof(int), stream);
        hipLaunchKernelGGL(k_hist, dim3((nnz + 255) / 256), dim3(256), 0, stream,
                           idxp, nnz, cursor);
        hipLaunchKernelGGL(k_scan, dim3(1), dim3(1024), 0, stream,
                           cursor, n, rowstart);
        hipLaunchKernelGGL(k_scatter, dim3((nnz + 255) / 256), dim3(256), 0, stream,
                           idxp, idxp + nnz, valp, nnz, cursor, ecol, eval);
    };

    auto propagate = [&](const int* idxp, const float* valp, int nnz,
                         const float* Bfeat, int nB, float* accA, float* accB) {
        const int n = U_ + nB;
        build_csr(idxp, valp, nnz, n);
        // acc init = layer-0 raw features
        hipMemcpyAsync(accA, users, (size_t)U_ * rowf * sizeof(float),
                       hipMemcpyDeviceToDevice, stream);
        hipMemcpyAsync(accB, Bfeat, (size_t)nB * rowf * sizeof(float),
                       hipMemcpyDeviceToDevice, stream);
        // layer 0: g = spmm(raw)/2 ; acc += l2norm(g)   (reads features direct)
        hipLaunchKernelGGL(k_layer, dim3((n + 3) / 4), dim3(256), 0, stream,
                           rowstart, ecol, eval, n, U_,
                           users, Bfeat - (size_t)U_ * rowf,
                           0.5f, gbuf, accA, accB);
        // layer 1: f = spmm(g)/3 ; acc += l2norm(f)
        hipLaunchKernelGGL(k_layer, dim3((n + 3) / 4), dim3(256), 0, stream,
                           rowstart, ecol, eval, n, n,
                           gbuf, gbuf,
                           1.0f / 3.0f, fbuf, accA, accB);
    };

    // item-level propagation over user-item graph
    propagate(ui_idx, ui_val, ui_nnz, items, I_, out_IL_u, acc_itm);

    // bundle aggregation: IL_b = agg @ IL_i
    build_csr(agg_idx, agg_val, agg_nnz, B_);
    hipLaunchKernelGGL(k_spmm_csr, dim3((B_ + 3) / 4), dim3(256), 0, stream,
                       rowstart, ecol, eval, B_, acc_itm, out_IL_b);

    // bundle-level propagation over user-bundle graph
    propagate(ub_idx, ub_val, ub_nnz, bundles, B_, out_BL_u, out_BL_b);

    // ingredient-augmented user-bundle propagation
    propagate(ubx_idx, ubx_val, ubx_nnz, bundles, B_, out_XL_u, out_XL_b);
}

// Round 3
// 1384.256 us; speedup vs baseline: 1.7463x; 1.3681x over previous
//
#include <hip/hip_runtime.h>

#define D 64
constexpr int U_ = 50000, B_ = 20000, I_ = 40000;

// ---------------- CSR build (per call, per graph) ----------------

__global__ void k_hist(const int* __restrict__ rows, int nnz, int* __restrict__ cnt) {
    int e = blockIdx.x * blockDim.x + threadIdx.x;
    if (e < nnz) atomicAdd(&cnt[rows[e]], 1);
}

// Pass A: per-block sums over 1024-count tiles (256 thr x 4 counts).
__global__ void k_scanA(const int* __restrict__ cnt, int n, int* __restrict__ blksum) {
    __shared__ int sm[256];
    int t = threadIdx.x;
    int i0 = blockIdx.x * 1024 + t * 4;
    int s = 0;
    if (i0 + 3 < n) {
        int4 v = *(const int4*)(cnt + i0);
        s = v.x + v.y + v.z + v.w;
    } else {
        for (int k = 0; k < 4; k++) { int i = i0 + k; if (i < n) s += cnt[i]; }
    }
    sm[t] = s;
    __syncthreads();
    for (int off = 128; off; off >>= 1) {
        if (t < off) sm[t] += sm[t + off];
        __syncthreads();
    }
    if (t == 0) blksum[blockIdx.x] = sm[0];
}

// Pass B: single small block scans G (<=256) block sums -> exclusive offsets.
__global__ void k_scanB(int* __restrict__ blksum, int G) {
    __shared__ int sm[256];
    int t = threadIdx.x;
    sm[t] = (t < G) ? blksum[t] : 0;
    __syncthreads();
    for (int off = 1; off < 256; off <<= 1) {      // Hillis-Steele inclusive
        int v = (t >= off) ? sm[t - off] : 0;
        __syncthreads();
        sm[t] += v;
        __syncthreads();
    }
    if (t < G) blksum[t] = (t == 0) ? 0 : sm[t - 1];   // exclusive
}

// Pass C: intra-block exclusive scan + block offset -> rowstart & cursor.
__global__ void k_scanC(const int* __restrict__ cnt, int n,
                        const int* __restrict__ blkoff,
                        int* __restrict__ rowstart, int* __restrict__ cursor) {
    __shared__ int sm[256];
    int t = threadIdx.x;
    int i0 = blockIdx.x * 1024 + t * 4;
    int c0 = 0, c1 = 0, c2 = 0, c3 = 0;
    if (i0 + 3 < n) {
        int4 v = *(const int4*)(cnt + i0);
        c0 = v.x; c1 = v.y; c2 = v.z; c3 = v.w;
    } else {
        if (i0 + 0 < n) c0 = cnt[i0 + 0];
        if (i0 + 1 < n) c1 = cnt[i0 + 1];
        if (i0 + 2 < n) c2 = cnt[i0 + 2];
        if (i0 + 3 < n) c3 = cnt[i0 + 3];
    }
    int tsum = c0 + c1 + c2 + c3;
    sm[t] = tsum;
    __syncthreads();
    for (int off = 1; off < 256; off <<= 1) {      // inclusive scan of thread sums
        int v = (t >= off) ? sm[t - off] : 0;
        __syncthreads();
        sm[t] += v;
        __syncthreads();
    }
    int run = blkoff[blockIdx.x] + ((t == 0) ? 0 : sm[t - 1]);
    int o0 = run, o1 = o0 + c0, o2 = o1 + c1, o3 = o2 + c2;
    if (i0 + 0 < n) { rowstart[i0 + 0] = o0; cursor[i0 + 0] = o0; if (i0 + 0 == n - 1) rowstart[n] = o0 + c0; }
    if (i0 + 1 < n) { rowstart[i0 + 1] = o1; cursor[i0 + 1] = o1; if (i0 + 1 == n - 1) rowstart[n] = o1 + c1; }
    if (i0 + 2 < n) { rowstart[i0 + 2] = o2; cursor[i0 + 2] = o2; if (i0 + 2 == n - 1) rowstart[n] = o2 + c2; }
    if (i0 + 3 < n) { rowstart[i0 + 3] = o3; cursor[i0 + 3] = o3; if (i0 + 3 == n - 1) rowstart[n] = o3 + c3; }
}

__global__ void k_scatter(const int* __restrict__ rows, const int* __restrict__ cols,
                          const float* __restrict__ val, int nnz,
                          int* __restrict__ cursor, int* __restrict__ ecol,
                          float* __restrict__ eval) {
    int e = blockIdx.x * blockDim.x + threadIdx.x;
    if (e >= nnz) return;
    int pos = atomicAdd(&cursor[rows[e]], 1);
    ecol[pos] = cols[e];
    eval[pos] = val[e];
}

// ---------------- fused CSR-SpMM + scale + l2norm + acc ----------------
// One 64-lane wave per destination row; row accumulated in registers.
__global__ void k_layer(const int* __restrict__ rowstart, const int* __restrict__ ecol,
                        const float* __restrict__ eval, int n, int nsplit,
                        const float* __restrict__ xA, const float* __restrict__ xB_adj,
                        float inv, float* __restrict__ fout,
                        float* __restrict__ accA, float* __restrict__ accB) {
    int row = (blockIdx.x << 2) + (threadIdx.x >> 6);
    if (row >= n) return;
    int lane = threadIdx.x & 63;
    int s = rowstart[row], e = rowstart[row + 1];
    float acc = 0.f;
    for (int base = s; base < e; base += 64) {
        int jn = e - base; if (jn > 64) jn = 64;
        int li = base + (lane < jn ? lane : jn - 1);   // clamped vector load
        int   cj = ecol[li];
        float vj = eval[li];
        for (int j = 0; j < jn; j++) {
            int   c = __shfl(cj, j, 64);
            float v = __shfl(vj, j, 64);
            const float* xp = (c < nsplit) ? xA : xB_adj;   // wave-uniform select
            acc += v * xp[(size_t)c * D + lane];
        }
    }
    float v = acc * inv;
    fout[(size_t)row * D + lane] = v;
    float sq = v * v;
    #pragma unroll
    for (int off = 32; off; off >>= 1) sq += __shfl_xor(sq, off, 64);
    float r = v / fmaxf(sqrtf(sq), 1e-12f);
    if (row < U_) accA[(size_t)row * D + lane] += r;
    else          accB[(size_t)(row - U_) * D + lane] += r;
}

// Plain CSR-SpMM (bundle aggregation): y[row] = sum val * x[col]
__global__ void k_spmm_csr(const int* __restrict__ rowstart, const int* __restrict__ ecol,
                           const float* __restrict__ eval, int n,
                           const float* __restrict__ x, float* __restrict__ y) {
    int row = (blockIdx.x << 2) + (threadIdx.x >> 6);
    if (row >= n) return;
    int lane = threadIdx.x & 63;
    int s = rowstart[row], e = rowstart[row + 1];
    float acc = 0.f;
    for (int base = s; base < e; base += 64) {
        int jn = e - base; if (jn > 64) jn = 64;
        int li = base + (lane < jn ? lane : jn - 1);
        int   cj = ecol[li];
        float vj = eval[li];
        for (int j = 0; j < jn; j++) {
            int   c = __shfl(cj, j, 64);
            float v = __shfl(vj, j, 64);
            acc += v * x[(size_t)c * D + lane];
        }
    }
    y[(size_t)row * D + lane] = acc;
}

extern "C" void kernel_launch(void* const* d_in, const int* in_sizes, int n_in,
                              void* d_out, int out_size, void* d_ws, size_t ws_size,
                              hipStream_t stream) {
    const float* users   = (const float*)d_in[0];
    const float* bundles = (const float*)d_in[1];
    const float* items   = (const float*)d_in[2];
    const int*   ui_idx  = (const int*)d_in[3];
    const float* ui_val  = (const float*)d_in[4];
    const int*   ub_idx  = (const int*)d_in[5];
    const float* ub_val  = (const float*)d_in[6];
    const int*   ubx_idx = (const int*)d_in[7];
    const float* ubx_val = (const float*)d_in[8];
    const int*   agg_idx = (const int*)d_in[9];
    const float* agg_val = (const float*)d_in[10];
    const int ui_nnz  = in_sizes[4];
    const int ub_nnz  = in_sizes[6];
    const int ubx_nnz = in_sizes[8];
    const int agg_nnz = in_sizes[10];

    float* out = (float*)d_out;
    const size_t rowf = (size_t)D;

    // ---- workspace carve-up ----
    const size_t NMAX   = (size_t)(U_ + I_) * D;      // 5.76M floats
    const int    NNZMAX = 2000000;                    // ui graph (largest)
    const int    NROWMX = U_ + I_ + 1;
    float* fbuf    = (float*)d_ws;                    // 23.04 MB
    float* gbuf    = fbuf + NMAX;                     // 23.04 MB
    float* acc_itm = gbuf + NMAX;                     // 10.24 MB
    float* eval    = acc_itm + (size_t)I_ * D;        //  8.0 MB
    int*   ecol    = (int*)(eval + NNZMAX);           //  8.0 MB
    int*   rowstart= ecol + NNZMAX;                   //  ~0.36 MB
    int*   cursor  = rowstart + NROWMX;               //  ~0.36 MB
    int*   cnt     = cursor + NROWMX;                 //  ~0.36 MB
    int*   blksum  = cnt + NROWMX;                    //  1 KB

    // ---- output layout ----
    float* out_IL_u = out;
    float* out_BL_u = out + (size_t)U_ * rowf;
    float* out_XL_u = out + (size_t)2 * U_ * rowf;
    float* out_IL_b = out + (size_t)3 * U_ * rowf;
    float* out_BL_b = out + (size_t)3 * U_ * rowf + (size_t)B_ * rowf;
    float* out_XL_b = out + (size_t)3 * U_ * rowf + (size_t)2 * B_ * rowf;

    auto build_csr = [&](const int* idxp, const float* valp, int nnz, int n) {
        const int G = (n + 1023) / 1024;   // <= 88
        hipMemsetAsync(cnt, 0, (size_t)n * sizeof(int), stream);
        hipLaunchKernelGGL(k_hist, dim3((nnz + 255) / 256), dim3(256), 0, stream,
                           idxp, nnz, cnt);
        hipLaunchKernelGGL(k_scanA, dim3(G), dim3(256), 0, stream, cnt, n, blksum);
        hipLaunchKernelGGL(k_scanB, dim3(1), dim3(256), 0, stream, blksum, G);
        hipLaunchKernelGGL(k_scanC, dim3(G), dim3(256), 0, stream,
                           cnt, n, blksum, rowstart, cursor);
        hipLaunchKernelGGL(k_scatter, dim3((nnz + 255) / 256), dim3(256), 0, stream,
                           idxp, idxp + nnz, valp, nnz, cursor, ecol, eval);
    };

    auto propagate = [&](const int* idxp, const float* valp, int nnz,
                         const float* Bfeat, int nB, float* accA, float* accB) {
        const int n = U_ + nB;
        build_csr(idxp, valp, nnz, n);
        // acc init = layer-0 raw features
        hipMemcpyAsync(accA, users, (size_t)U_ * rowf * sizeof(float),
                       hipMemcpyDeviceToDevice, stream);
        hipMemcpyAsync(accB, Bfeat, (size_t)nB * rowf * sizeof(float),
                       hipMemcpyDeviceToDevice, stream);
        // layer 0: g = spmm(raw)/2 ; acc += l2norm(g)   (reads features direct)
        hipLaunchKernelGGL(k_layer, dim3((n + 3) / 4), dim3(256), 0, stream,
                           rowstart, ecol, eval, n, U_,
                           users, Bfeat - (size_t)U_ * rowf,
                           0.5f, gbuf, accA, accB);
        // layer 1: f = spmm(g)/3 ; acc += l2norm(f)
        hipLaunchKernelGGL(k_layer, dim3((n + 3) / 4), dim3(256), 0, stream,
                           rowstart, ecol, eval, n, n,
                           gbuf, gbuf,
                           1.0f / 3.0f, fbuf, accA, accB);
    };

    // item-level propagation over user-item graph
    propagate(ui_idx, ui_val, ui_nnz, items, I_, out_IL_u, acc_itm);

    // bundle aggregation: IL_b = agg @ IL_i
    build_csr(agg_idx, agg_val, agg_nnz, B_);
    hipLaunchKernelGGL(k_spmm_csr, dim3((B_ + 3) / 4), dim3(256), 0, stream,
                       rowstart, ecol, eval, B_, acc_itm, out_IL_b);

    // bundle-level propagation over user-bundle graph
    propagate(ub_idx, ub_val, ub_nnz, bundles, B_, out_BL_u, out_BL_b);

    // ingredient-augmented user-bundle propagation
    propagate(ubx_idx, ubx_val, ubx_nnz, bundles, B_, out_XL_u, out_XL_b);
}